// Round 8
// baseline (61.427 us; speedup 1.0000x reference)
//
#include <hip/hip_runtime.h>
#include <hip/hip_bf16.h>
#include <math.h>

// BlockwiseDense: y[b,i,j,k] = sum_l quant(relu(cores[i,j,k,l])) * x[b, j*256+l]
// x: (128, 4096) f32, cores: (16,16,256,256) f32, out: (128,16,16,256) f32.
//
// v7: async-DMA pipeline. WG = (i,j) block, grid 256 (1 WG/CU), 256 thr.
//   - W streamed in 8 k-slabs (32 rows x 256 l = 32 KB f32) via
//     global_load_lds width=16, double-buffered: compute(t) || stage(t+1),
//     barrier drain = pipeline join, stage(t+2) issued after.
//   - global source pre-swizzled (o ^ ((o>>10&7)<<4)) so linear DMA dest =
//     swizzled layout; MFMA-phase ds_read_b128 is 2-way (free) not 16-way.
//   - quantize inline in the MFMA phase (raw f32 LDS -> a-frag), x4 wave
//     redundancy traded for zero extra barriers/buffers.
//   - x fragments bf16 (from d_ws) in 64 VGPRs, reused x8 slabs.

typedef __attribute__((ext_vector_type(4))) float f32x4;
typedef __attribute__((ext_vector_type(8))) short bf16x8;  // 8 bf16
typedef __attribute__((ext_vector_type(8))) short s16x8;

#define TAU   0.75f
#define G_INF 2.0f
#define G_MIN 0.001f

__device__ __forceinline__ short f2bf_rne(float f) {
    union { float f; unsigned u; } v; v.f = f;
    unsigned u = v.u;
    return (short)((u + 0x7FFFu + ((u >> 16) & 1u)) >> 16);
}

// async global->LDS, 16B per lane; dest = wave-uniform base + lane*16
__device__ __forceinline__ void gll16(const void* g, void* l) {
    typedef const unsigned int __attribute__((address_space(1)))* gp1;
    typedef unsigned int __attribute__((address_space(3)))* lp3;
    __builtin_amdgcn_global_load_lds((gp1)(const unsigned int*)g,
                                     (lp3)(unsigned int*)l, 16, 0, 0);
}

// ---- kernel 1: x f32 -> bf16 (1 MB, L2-resident thereafter) ----
__global__ __launch_bounds__(256)
void xcvt(const float* __restrict__ xin, short* __restrict__ xbf) {
    int idx = (blockIdx.x * 256 + threadIdx.x) * 8;
    f32x4 a = *(const f32x4*)(xin + idx);
    f32x4 b = *(const f32x4*)(xin + idx + 4);
    s16x8 o;
    o[0] = f2bf_rne(a[0]); o[1] = f2bf_rne(a[1]);
    o[2] = f2bf_rne(a[2]); o[3] = f2bf_rne(a[3]);
    o[4] = f2bf_rne(b[0]); o[5] = f2bf_rne(b[1]);
    o[6] = f2bf_rne(b[2]); o[7] = f2bf_rne(b[3]);
    *(s16x8*)(xbf + idx) = o;
}

// ---- kernel 2: fused quantize + blockwise GEMM, DMA-pipelined ----
template<bool XBF>
__global__ __launch_bounds__(256, 1)
void bd_fused(const float* __restrict__ x,
              const short* __restrict__ xbf,
              const float* __restrict__ cores,
              float* __restrict__ out)
{
    __shared__ unsigned char wraw[2][32768];   // raw f32 W slab double-buffer

    const int tid  = threadIdx.x;
    const int wave = tid >> 6;
    const int lane = tid & 63;
    const int l15  = lane & 15;
    const int l4   = lane >> 4;

    const int bid = blockIdx.x;
    const int j   = bid & 15;     // input block
    const int i   = bid >> 4;     // output block

    // quantization constants (f32, mirroring the numpy level construction)
    const float scale     = (G_INF - G_MIN) / (1.0f - expf(-TAU));
    const float inv_scale = 1.0f / scale;
    const float T0 = 1.0f + G_MIN * inv_scale;                 // t = T0 - w/scale
    const float kn = -(255.0f / TAU) * 0.69314718055994531f;   // n = kn*log2(t)
    const float c2 = -(TAU / 255.0f) * 1.44269504088896341f;   // lvl = Ac - scale*exp2(c2*g)
    const float Ac = G_MIN + scale;
    const float rho = expf(-TAU / 255.0f);
    const float Df  = 1.0f - logf((1.0f + rho) * 0.5f) / logf(rho);  // ~0.50037
    // midpoint rule: g = floor(nr + Df)  (levels geometric in t, w<->t affine)

    const unsigned char* wblk =
        (const unsigned char*)(cores + (((size_t)(i * 16 + j)) << 16));

    // stage slab t (32 KB) into buffer b: 8 gll16 per thread, src pre-swizzled
    auto STAGE = [&](int t, int b) {
        #pragma unroll
        for (int n = 0; n < 8; ++n) {
            int o   = n * 4096 + tid * 16;                      // linear LDS off
            int src = o ^ ((((unsigned)o >> 10) & 7) << 4);     // inverse swizzle
            gll16(wblk + (size_t)t * 32768 + src,
                  &wraw[b][n * 4096 + wave * 1024]);            // wave-uniform base
        }
    };

    // ---- prologue: stage slabs 0,1; load x fragments (reused x8 slabs) ----
    STAGE(0, 0);
    STAGE(1, 1);

    const int brow0 = wave * 32;
    bf16x8 bfr[8][2];    // [s: l-step][mt: batch 16-tile] -> 64 VGPRs
    const short* xb = xbf + (size_t)(brow0 + l15) * 4096 + j * 256 + l4 * 8;
    const float* xf = x   + (size_t)(brow0 + l15) * 4096 + j * 256 + l4 * 8;
    #pragma unroll
    for (int s = 0; s < 8; ++s) {
        #pragma unroll
        for (int mt = 0; mt < 2; ++mt) {
            if (XBF) {
                bfr[s][mt] = *(const bf16x8*)(xb + (size_t)mt * 65536 + s * 32);
            } else {
                const float* p = xf + (size_t)mt * 65536 + s * 32;
                f32x4 v0 = *(const f32x4*)p;
                f32x4 v1 = *(const f32x4*)(p + 4);
                bf16x8 bb;
                bb[0] = f2bf_rne(v0[0]); bb[1] = f2bf_rne(v0[1]);
                bb[2] = f2bf_rne(v0[2]); bb[3] = f2bf_rne(v0[3]);
                bb[4] = f2bf_rne(v1[0]); bb[5] = f2bf_rne(v1[1]);
                bb[6] = f2bf_rne(v1[2]); bb[7] = f2bf_rne(v1[3]);
                bfr[s][mt] = bb;
            }
        }
    }

    __syncthreads();   // vmcnt(0) drain: slabs 0,1 resident, x in regs

    // ---- main loop: 8 k-slabs of 32 rows ----
    for (int t = 0; t < 8; ++t) {
        const unsigned char* buf = wraw[t & 1];

        f32x4 acc[2][2];   // [nt: k 16-tile][mt: batch 16-tile]
        #pragma unroll
        for (int nt = 0; nt < 2; ++nt)
            #pragma unroll
            for (int mt = 0; mt < 2; ++mt)
                acc[nt][mt] = (f32x4){0.f, 0.f, 0.f, 0.f};

        #pragma unroll
        for (int s = 0; s < 8; ++s) {
            #pragma unroll
            for (int nt = 0; nt < 2; ++nt) {
                // A-frag: W[k = nt*16+l15][l = s*32 + l4*8 .. +7], raw f32
                int r  = nt * 16 + l15;
                int a  = r * 1024 + s * 128 + l4 * 32;
                int sw = (r & 7) << 4;
                f32x4 v0 = *(const f32x4*)(buf + ((a     ) ^ sw));
                f32x4 v1 = *(const f32x4*)(buf + ((a + 16) ^ sw));
                bf16x8 afr;
                #pragma unroll
                for (int e = 0; e < 8; ++e) {
                    float w = fmaxf(e < 4 ? v0[e & 3] : v1[e & 3], 0.0f);
                    float tt = fmaf(w, -inv_scale, T0);   // = exp(-tau*n/255)
                    tt = fmaxf(tt, 1e-8f);
                    float nr = kn * __log2f(tt);          // continuous level idx
                    float g  = floorf(nr + Df);           // nearest level (midpoint)
                    float qv = fmaf(exp2f(c2 * g), -scale, Ac);
                    afr[e] = f2bf_rne(qv);
                }
                acc[nt][0] = __builtin_amdgcn_mfma_f32_16x16x32_bf16(afr, bfr[s][0], acc[nt][0], 0, 0, 0);
                acc[nt][1] = __builtin_amdgcn_mfma_f32_16x16x32_bf16(afr, bfr[s][1], acc[nt][1], 0, 0, 0);
            }
        }

        if (t < 7) {
            __syncthreads();          // drain stage(t+1) (had compute(t) to fly)
            if (t + 2 < 8) STAGE(t + 2, t & 1);   // refill the buffer just freed
        }

        // store after the barrier: write-acks retire under compute(t+1)
        #pragma unroll
        for (int nt = 0; nt < 2; ++nt) {
            #pragma unroll
            for (int mt = 0; mt < 2; ++mt) {
                int b  = brow0 + mt * 16 + l15;
                int kg = t * 32 + nt * 16 + (l4 << 2);
                *(f32x4*)(out + (((size_t)((b * 16 + i) * 16 + j)) << 8) + kg) = acc[nt][mt];
            }
        }
    }
}

extern "C" void kernel_launch(void* const* d_in, const int* in_sizes, int n_in,
                              void* d_out, int out_size, void* d_ws, size_t ws_size,
                              hipStream_t stream) {
    const float* x     = (const float*)d_in[0];
    const float* cores = (const float*)d_in[1];
    float* out = (float*)d_out;

    const size_t xbytes = (size_t)128 * 4096 * sizeof(short);  // 1 MB
    if (ws_size >= xbytes) {
        short* xbf = (short*)d_ws;
        xcvt<<<dim3(256), dim3(256), 0, stream>>>(x, xbf);
        bd_fused<true><<<dim3(256), dim3(256), 0, stream>>>(x, xbf, cores, out);
    } else {
        bd_fused<false><<<dim3(256), dim3(256), 0, stream>>>(x, nullptr, cores, out);
    }
}

// Round 9
// 33.499 us; speedup vs baseline: 1.8337x; 1.8337x over previous
//
#include <hip/hip_runtime.h>
#include <hip/hip_bf16.h>
#include <math.h>

// BlockwiseDense: y[b,i,j,k] = sum_l quant(relu(cores[i,j,k,l])) * x[b, j*256+l]
// x: (128, 4096) f32, cores: (16,16,256,256) f32, out: (128,16,16,256) f32.
//
// v8: 3-stage pipelined slab loop, quantize-once, DMA-staged, 3 WG/CU.
//   WG = (i, j, 64 k-rows) -> grid 1024. 4 slabs of 16 k-rows per WG.
//   Region t (1 barrier each):  issue DMA(t+1) -> raw[(t+1)&1]
//                               quantize(t):  raw[t&1] -> wq[t&1] (once/elem)
//                               MFMA(t-1) from wq[(t-1)&1] + store
//   Parity keeps all same-region buffers disjoint; barrier vmcnt(0) = join.
//   LDS 48 KB -> 3 WG/CU (12 waves/CU); grid 4/CU -> refill generation.
//   x bf16 fragments in regs (reused x4 slabs); raw slab read linearly (no
//   swizzle on DMA path); wq uses v1's verified swizzle + layouts.

typedef __attribute__((ext_vector_type(4))) float f32x4;
typedef __attribute__((ext_vector_type(8))) short bf16x8;  // 8 bf16
typedef __attribute__((ext_vector_type(8))) short s16x8;

#define TAU   0.75f
#define G_INF 2.0f
#define G_MIN 0.001f

__device__ __forceinline__ short f2bf_rne(float f) {
    union { float f; unsigned u; } v; v.f = f;
    unsigned u = v.u;
    return (short)((u + 0x7FFFu + ((u >> 16) & 1u)) >> 16);
}

// async global->LDS, 16B per lane; LDS dest = wave-uniform base + lane*16
__device__ __forceinline__ void gll16(const void* g, void* l) {
    typedef const unsigned int __attribute__((address_space(1)))* gp1;
    typedef unsigned int __attribute__((address_space(3)))* lp3;
    __builtin_amdgcn_global_load_lds((gp1)(const unsigned int*)g,
                                     (lp3)(unsigned int*)l, 16, 0, 0);
}

// ---- kernel 1: x f32 -> bf16 (1 MB, L2-resident thereafter) ----
__global__ __launch_bounds__(256)
void xcvt(const float* __restrict__ xin, short* __restrict__ xbf) {
    int idx = (blockIdx.x * 256 + threadIdx.x) * 8;
    f32x4 a = *(const f32x4*)(xin + idx);
    f32x4 b = *(const f32x4*)(xin + idx + 4);
    s16x8 o;
    o[0] = f2bf_rne(a[0]); o[1] = f2bf_rne(a[1]);
    o[2] = f2bf_rne(a[2]); o[3] = f2bf_rne(a[3]);
    o[4] = f2bf_rne(b[0]); o[5] = f2bf_rne(b[1]);
    o[6] = f2bf_rne(b[2]); o[7] = f2bf_rne(b[3]);
    *(s16x8*)(xbf + idx) = o;
}

// ---- kernel 2: fused quantize + blockwise GEMM, pipelined ----
template<bool XBF>
__global__ __launch_bounds__(256, 3)
void bd_fused(const float* __restrict__ x,
              const short* __restrict__ xbf,
              const float* __restrict__ cores,
              float* __restrict__ out)
{
    __shared__ float         raw[2][4096];   // 2 x 16 KB raw f32 slabs
    __shared__ unsigned char wq[2][8192];    // 2 x (16 rows x 256 bf16), swizzled

    const int tid  = threadIdx.x;
    const int wave = tid >> 6;
    const int lane = tid & 63;
    const int l15  = lane & 15;
    const int l4   = lane >> 4;

    const int bid = blockIdx.x;
    const int ns  = bid & 3;          // which 64-k slice
    const int j   = (bid >> 2) & 15;  // input block
    const int i   = bid >> 6;         // output block
    const int k0  = ns * 64;

    // quantization constants (f32, mirroring the numpy level construction)
    const float scale     = (G_INF - G_MIN) / (1.0f - expf(-TAU));
    const float inv_scale = 1.0f / scale;
    const float T0 = 1.0f + G_MIN * inv_scale;                 // t = T0 - w/scale
    const float kn = -(255.0f / TAU) * 0.69314718055994531f;   // n = kn*log2(t)
    const float c2 = -(TAU / 255.0f) * 1.44269504088896341f;   // lvl = Ac - scale*exp2(c2*g)
    const float Ac = G_MIN + scale;
    const float rho = expf(-TAU / 255.0f);
    const float Df  = 1.0f - logf((1.0f + rho) * 0.5f) / logf(rho);  // ~0.50037
    // nearest level: g = floor(nr + Df)   (exact midpoint rule in log-space)

    const unsigned char* wblk =
        (const unsigned char*)(cores + (((size_t)(i * 16 + j)) << 16)
                                     + ((size_t)k0 << 8));

    // stage slab t (16 rows x 1 KB) into raw[b]: 4 gll16 per thread
    auto STAGE = [&](int t, int b) {
        #pragma unroll
        for (int n = 0; n < 4; ++n) {
            int o = n * 4096 + tid * 16;               // linear byte offset
            gll16(wblk + (size_t)t * 16384 + o,
                  (unsigned char*)&raw[b][0] + n * 4096 + wave * 1024);
        }
    };

    // ---- prologue: DMA slab 0; load x fragments (reused x4 slabs) ----
    STAGE(0, 0);

    const int brow0 = wave * 32;
    bf16x8 bfr[8][2];    // [s: l-step][mt: batch 16-tile] -> 64 VGPRs
    const short* xb = xbf + (size_t)(brow0 + l15) * 4096 + j * 256 + l4 * 8;
    const float* xf = x   + (size_t)(brow0 + l15) * 4096 + j * 256 + l4 * 8;
    #pragma unroll
    for (int s = 0; s < 8; ++s) {
        #pragma unroll
        for (int mt = 0; mt < 2; ++mt) {
            if (XBF) {
                bfr[s][mt] = *(const bf16x8*)(xb + (size_t)mt * 65536 + s * 32);
            } else {
                const float* p = xf + (size_t)mt * 65536 + s * 32;
                f32x4 v0 = *(const f32x4*)p;
                f32x4 v1 = *(const f32x4*)(p + 4);
                bf16x8 bb;
                bb[0] = f2bf_rne(v0[0]); bb[1] = f2bf_rne(v0[1]);
                bb[2] = f2bf_rne(v0[2]); bb[3] = f2bf_rne(v0[3]);
                bb[4] = f2bf_rne(v1[0]); bb[5] = f2bf_rne(v1[1]);
                bb[6] = f2bf_rne(v1[2]); bb[7] = f2bf_rne(v1[3]);
                bfr[s][mt] = bb;
            }
        }
    }

    __syncthreads();   // drains DMA(0) + x loads

    // ---- 4 pipeline regions + epilogue ----
    #pragma unroll
    for (int t = 0; t < 4; ++t) {
        // (1) issue next slab's DMA: flies across this whole region
        if (t < 3) STAGE(t + 1, (t + 1) & 1);

        // (2) quantize slab t: 16 elems/thread, raw[t&1] -> wq[t&1]
        {
            const float* rb = &raw[t & 1][0] + tid * 16;   // 64B linear read
            f32x4 v0 = *(const f32x4*)rb;
            f32x4 v1 = *(const f32x4*)(rb + 4);
            f32x4 v2 = *(const f32x4*)(rb + 8);
            f32x4 v3 = *(const f32x4*)(rb + 12);
            s16x8 q0, q1;
            #pragma unroll
            for (int e = 0; e < 16; ++e) {
                float wv = e < 4 ? v0[e & 3] : e < 8 ? v1[e & 3]
                         : e < 12 ? v2[e & 3] : v3[e & 3];
                float w  = fmaxf(wv, 0.0f);
                float tt = fmaf(w, -inv_scale, T0);   // = exp(-tau*n/255) at w
                tt = fmaxf(tt, 1e-8f);
                float nr = kn * __log2f(tt);          // continuous level index
                float g  = floorf(nr + Df);           // nearest level
                float qv = fmaf(exp2f(c2 * g), -scale, Ac);
                if (e < 8) q0[e] = f2bf_rne(qv); else q1[e & 7] = f2bf_rne(qv);
            }
            int r    = tid >> 4;                      // local k row, 0..15
            int base = r * 512 + (tid & 15) * 32;     // byte col within row
            *(s16x8*)(&wq[t & 1][0] + ((base     ) ^ ((r & 7) << 4))) = q0;
            *(s16x8*)(&wq[t & 1][0] + ((base + 16) ^ ((r & 7) << 4))) = q1;
        }

        // (3) MFMA + store for slab t-1 (overlaps quantize above)
        if (t > 0) {
            const unsigned char* qb = &wq[(t - 1) & 1][0];
            f32x4 a0 = (f32x4){0.f, 0.f, 0.f, 0.f};
            f32x4 a1 = (f32x4){0.f, 0.f, 0.f, 0.f};
            #pragma unroll
            for (int s = 0; s < 8; ++s) {
                int off = (l15 * 512 + s * 64 + l4 * 16) ^ ((l15 & 7) << 4);
                bf16x8 afr = *(const bf16x8*)(qb + off);
                a0 = __builtin_amdgcn_mfma_f32_16x16x32_bf16(afr, bfr[s][0], a0, 0, 0, 0);
                a1 = __builtin_amdgcn_mfma_f32_16x16x32_bf16(afr, bfr[s][1], a1, 0, 0, 0);
            }
            int kg = k0 + (t - 1) * 16 + (l4 << 2);
            int b0 = brow0 + l15;
            *(f32x4*)(out + (((size_t)((b0 * 16 + i) * 16 + j)) << 8) + kg) = a0;
            int b1 = brow0 + 16 + l15;
            *(f32x4*)(out + (((size_t)((b1 * 16 + i) * 16 + j)) << 8) + kg) = a1;
        }

        __syncthreads();   // join: DMA(t+1) resident, wq(t) visible
    }

    // epilogue: slab 3
    {
        const unsigned char* qb = &wq[1][0];
        f32x4 a0 = (f32x4){0.f, 0.f, 0.f, 0.f};
        f32x4 a1 = (f32x4){0.f, 0.f, 0.f, 0.f};
        #pragma unroll
        for (int s = 0; s < 8; ++s) {
            int off = (l15 * 512 + s * 64 + l4 * 16) ^ ((l15 & 7) << 4);
            bf16x8 afr = *(const bf16x8*)(qb + off);
            a0 = __builtin_amdgcn_mfma_f32_16x16x32_bf16(afr, bfr[s][0], a0, 0, 0, 0);
            a1 = __builtin_amdgcn_mfma_f32_16x16x32_bf16(afr, bfr[s][1], a1, 0, 0, 0);
        }
        int kg = k0 + 48 + (l4 << 2);
        int b0 = brow0 + l15;
        *(f32x4*)(out + (((size_t)((b0 * 16 + i) * 16 + j)) << 8) + kg) = a0;
        int b1 = brow0 + 16 + l15;
        *(f32x4*)(out + (((size_t)((b1 * 16 + i) * 16 + j)) << 8) + kg) = a1;
    }
}

extern "C" void kernel_launch(void* const* d_in, const int* in_sizes, int n_in,
                              void* d_out, int out_size, void* d_ws, size_t ws_size,
                              hipStream_t stream) {
    const float* x     = (const float*)d_in[0];
    const float* cores = (const float*)d_in[1];
    float* out = (float*)d_out;

    const size_t xbytes = (size_t)128 * 4096 * sizeof(short);  // 1 MB
    if (ws_size >= xbytes) {
        short* xbf = (short*)d_ws;
        xcvt<<<dim3(256), dim3(256), 0, stream>>>(x, xbf);
        bd_fused<true><<<dim3(1024), dim3(256), 0, stream>>>(x, xbf, cores, out);
    } else {
        bd_fused<false><<<dim3(1024), dim3(256), 0, stream>>>(x, nullptr, cores, out);
    }
}